// Round 7
// baseline (172.561 us; speedup 1.0000x reference)
//
#include <hip/hip_runtime.h>

typedef unsigned short ushort_t;
typedef __attribute__((ext_vector_type(8)))  short  short8;
typedef __attribute__((ext_vector_type(4)))  short  short4v;
typedef __attribute__((ext_vector_type(4)))  float  float4v;
typedef __attribute__((ext_vector_type(4)))  int    int4v;

#define N_NODES 4096
#define NHEADS  4
#define DK      128
#define ODIM    512
#define KDIM    512

__device__ __forceinline__ float bf2f(ushort_t u) {
    return __uint_as_float(((unsigned)u) << 16);
}
__device__ __forceinline__ ushort_t f2bf_rne(float f) {
    unsigned u = __float_as_uint(f);
    u += 0x7fffu + ((u >> 16) & 1u);
    return (ushort_t)(u >> 16);
}

// ---------------------------------------------------------------------------
// Kernel 1 (fused): mask bit-pack + dtype flag + W transpose + sl/sr zeroing.
// ---------------------------------------------------------------------------
__global__ __launch_bounds__(256) void pack_mask_k(const int* __restrict__ A,
                                                   unsigned long long* __restrict__ P,
                                                   const ushort_t* __restrict__ Hraw,
                                                   int* __restrict__ flag,
                                                   const void* __restrict__ W,
                                                   ushort_t* __restrict__ WT,
                                                   float* __restrict__ sl,
                                                   float* __restrict__ sr)
{
    __shared__ ushort_t lt[64][72];
    __shared__ int dcnt[4];
    const int tid = threadIdx.x;
    const int bx  = blockIdx.x;

    if (bx == 0 && tid < 64) {
        const int lane = tid;
        int cnt = 0;
        #pragma unroll
        for (int s = 0; s < 16; ++s) {
            ushort_t v = Hraw[(lane * 16 + s) * 2];
            int e = (v >> 7) & 0xFF;
            cnt += (((e >= 90) && (e <= 140)) || (v == 0)) ? 1 : 0;
        }
        #pragma unroll
        for (int off = 32; off; off >>= 1) cnt += __shfl_down(cnt, off);
        if (lane == 0) *flag = (cnt < 768) ? 1 : 0;
    }

    // ---- mask pack (all blocks) ----
    {
        const int lane  = tid & 63;
        const int flat4 = bx * 256 + tid;             // index in units of int4
        const int row   = flat4 >> 10;                // (flat4*4) >> 12
        const int col0  = (flat4 << 2) & 4095;
        const int4v a   = ((const int4v*)A)[flat4];
        unsigned nib = 0;
        #pragma unroll
        for (int j = 0; j < 4; ++j)
            nib |= ((a[j] != 0) || (row == col0 + j)) ? (1u << j) : 0u;
        unsigned long long v = (unsigned long long)nib << ((lane & 15) * 4);
        v |= __shfl_xor(v, 1);
        v |= __shfl_xor(v, 2);
        v |= __shfl_xor(v, 4);
        v |= __shfl_xor(v, 8);
        if ((lane & 15) == 0) P[flat4 >> 4] = v;
    }

    // ---- zero sl/sr (blocks 64..95): 8192 threads x one float4 ----
    if (bx >= 64 && bx < 96) {
        const int idx = (bx - 64) * 256 + tid;        // 0..8191
        float4v z;
        #pragma unroll
        for (int e = 0; e < 4; ++e) z[e] = 0.f;
        if (idx < 4096) ((float4v*)sl)[idx] = z;
        else            ((float4v*)sr)[idx - 4096] = z;
    }

    // ---- W transpose (blocks 0..63) ----
    if (bx < 64) {
        // block-local dtype detection (same 1024 samples as the global flag)
        int cnt = 0;
        #pragma unroll
        for (int s = 0; s < 4; ++s) {
            ushort_t v = Hraw[(tid * 4 + s) * 2];
            int e = (v >> 7) & 0xFF;
            cnt += (((e >= 90) && (e <= 140)) || (v == 0)) ? 1 : 0;
        }
        #pragma unroll
        for (int off = 32; off; off >>= 1) cnt += __shfl_down(cnt, off);
        if ((tid & 63) == 0) dcnt[tid >> 6] = cnt;
        __syncthreads();
        const int f32 = (dcnt[0] + dcnt[1] + dcnt[2] + dcnt[3]) < 768;

        const int ti = bx >> 3, tj = bx & 7;
        const int r = tid >> 2, c2 = tid & 3;
        const size_t eo = (size_t)(ti * 64 + r) * KDIM + tj * 64 + c2 * 16;
        if (f32) {
            const float4v* src = (const float4v*)((const float*)W + eo);
            float4v f0 = src[0], f1 = src[1], f2 = src[2], f3 = src[3];
            #pragma unroll
            for (int e = 0; e < 4; ++e) {
                lt[r][c2 * 16 +  0 + e] = f2bf_rne(f0[e]);
                lt[r][c2 * 16 +  4 + e] = f2bf_rne(f1[e]);
                lt[r][c2 * 16 +  8 + e] = f2bf_rne(f2[e]);
                lt[r][c2 * 16 + 12 + e] = f2bf_rne(f3[e]);
            }
        } else {
            const short8* src = (const short8*)((const ushort_t*)W + eo);
            short8 v0 = src[0];
            short8 v1 = src[1];
            *(short8*)&lt[r][c2 * 16]     = v0;
            *(short8*)&lt[r][c2 * 16 + 8] = v1;
        }
        __syncthreads();
        #pragma unroll
        for (int itr = 0; itr < 2; ++itr) {
            int idx = itr * 256 + tid;
            int n = idx >> 3, c = idx & 7;
            short8 vv;
            #pragma unroll
            for (int e = 0; e < 8; ++e) vv[e] = (short)lt[c * 8 + e][n];
            *(short8*)(WT + (size_t)(tj * 64 + n) * KDIM + ti * 64 + c * 8) = vv;
        }
    }
}

// ---------------------------------------------------------------------------
// Kernel 2 (fused): WhT[n][i] = (H @ W)[i][n] + sl/sr partial accumulation.
// ---------------------------------------------------------------------------
__global__ __launch_bounds__(256) void gemm_wht_dual_k(const void* __restrict__ H,
                                                       const ushort_t* __restrict__ WT,
                                                       ushort_t* __restrict__ WhT,
                                                       const int* __restrict__ flag,
                                                       const void* __restrict__ al,
                                                       const void* __restrict__ ar,
                                                       float* __restrict__ sl,
                                                       float* __restrict__ sr)
{
    __shared__ ushort_t lt[64][72];
    const int f32 = *flag;
    const int tid  = threadIdx.x;
    const int lane = tid & 63;
    const int wid  = tid >> 6;
    const int quad = lane >> 4;
    const int l15  = lane & 15;
    const int bm = blockIdx.x & 63, bn = blockIdx.x >> 6;
    const int i0 = bm * 64, n0 = bn * 64;

    const size_t aoff = (size_t)(i0 + wid * 16 + l15) * KDIM + quad * 8;
    const short8* bp0 = (const short8*)(WT + (size_t)(n0 +  0 + l15) * KDIM) + quad;
    const short8* bp1 = (const short8*)(WT + (size_t)(n0 + 16 + l15) * KDIM) + quad;
    const short8* bp2 = (const short8*)(WT + (size_t)(n0 + 32 + l15) * KDIM) + quad;
    const short8* bp3 = (const short8*)(WT + (size_t)(n0 + 48 + l15) * KDIM) + quad;

    float4v acc0, acc1, acc2, acc3;
    #pragma unroll
    for (int e = 0; e < 4; ++e) { acc0[e] = 0.f; acc1[e] = 0.f; acc2[e] = 0.f; acc3[e] = 0.f; }

    #pragma unroll 4
    for (int k8 = 0; k8 < 64; k8 += 4) {
        short8 a;
        if (f32) {
            const float4v* fp = (const float4v*)((const float*)H + aoff + (size_t)k8 * 8);
            float4v x0 = fp[0], x1 = fp[1];
            #pragma unroll
            for (int e = 0; e < 4; ++e) {
                a[e]     = (short)f2bf_rne(x0[e]);
                a[4 + e] = (short)f2bf_rne(x1[e]);
            }
        } else {
            a = *(const short8*)((const ushort_t*)H + aoff + (size_t)k8 * 8);
        }
        acc0 = __builtin_amdgcn_mfma_f32_16x16x32_bf16(a, bp0[k8], acc0, 0, 0, 0);
        acc1 = __builtin_amdgcn_mfma_f32_16x16x32_bf16(a, bp1[k8], acc1, 0, 0, 0);
        acc2 = __builtin_amdgcn_mfma_f32_16x16x32_bf16(a, bp2[k8], acc2, 0, 0, 0);
        acc3 = __builtin_amdgcn_mfma_f32_16x16x32_bf16(a, bp3[k8], acc3, 0, 0, 0);
    }

    #pragma unroll
    for (int r = 0; r < 4; ++r) {
        int m = wid * 16 + quad * 4 + r;
        lt[ 0 + l15][m] = f2bf_rne(acc0[r]);
        lt[16 + l15][m] = f2bf_rne(acc1[r]);
        lt[32 + l15][m] = f2bf_rne(acc2[r]);
        lt[48 + l15][m] = f2bf_rne(acc3[r]);
    }
    __syncthreads();
    #pragma unroll
    for (int itr = 0; itr < 2; ++itr) {
        int idx = itr * 256 + tid;
        int n = idx >> 3, c = idx & 7;
        short8 v = *(const short8*)&lt[n][c * 8];
        *(short8*)(WhT + (size_t)(n0 + n) * N_NODES + i0 + c * 8) = v;
    }

    // ---- fused slsr partials over this block's 64 d-values ----
    {
        const int h2 = n0 >> 7;          // head
        const int d0 = n0 & 127;         // d offset within head
        const int m  = tid >> 2;         // output row = i0 + m
        const int part = tid & 3;
        float psl = 0.f, psr = 0.f;
        #pragma unroll
        for (int k = 0; k < 16; ++k) {
            int n = part * 16 + k;
            float wv = bf2f(lt[n][m]);
            float av = f32 ? ((const float*)al)[h2 * DK + d0 + n]
                           : bf2f(((const ushort_t*)al)[h2 * DK + d0 + n]);
            float bv = f32 ? ((const float*)ar)[h2 * DK + d0 + n]
                           : bf2f(((const ushort_t*)ar)[h2 * DK + d0 + n]);
            psl += wv * av;
            psr += wv * bv;
        }
        psl += __shfl_down(psl, 2); psl += __shfl_down(psl, 1);
        psr += __shfl_down(psr, 2); psr += __shfl_down(psr, 1);
        if (part == 0) {
            atomicAdd(&sl[h2 * N_NODES + i0 + m], psl);
            atomicAdd(&sr[h2 * N_NODES + i0 + m], psr);
        }
    }
}

// ---------------------------------------------------------------------------
// Kernel 3 v17: 8 waves sharing one 64j x 128d window stream.
// v16 post-mortem: splitting j into two 32j streams halved the LDS row
// stride to 64B -> rows alternate 16-bank halves -> 8 accesses/bank on
// ds_read_b128 (SQ_LDS_BANK_CONFLICT 0 -> 4.45M, ~17% of kernel).  The
// 128B-row layout + quad^(l15&7) swizzle of v15 is beat-conflict-free
// (measured 0).  v17 keeps 8 waves (4 waves/SIMD, the v16 occupancy win)
// but waves = (row-group wq 0..3) x (j-half js 0..1) OF THE SAME WINDOW:
// per window a wave computes its 16 rows x its 32j chunk (one pf short8,
// 8 MFMAs).  Same total VALU/MFMA as v16, same per-wave VALU, conflict-free
// reads.  One shared window stream: 8 waves x 2 DMA calls, 3-buffer
// rotation, counted vmcnt(2), one raw s_barrier per window, DMA iw+2
// post-barrier.  js-pairs merge in epilogue (v16's).  LDS 72KB, VGPR ~52.
// ---------------------------------------------------------------------------
__global__ __launch_bounds__(512, 4) void attn_split_k(const ushort_t* __restrict__ WhT,
                                                       const unsigned* __restrict__ Apack,
                                                       const float* __restrict__ sl,
                                                       const float* __restrict__ sr,
                                                       float* __restrict__ Npart,
                                                       float* __restrict__ Dpart)
{
    __shared__ char smem[73728] __attribute__((aligned(16)));
    float*    srs  = (float*)smem;                            // 2048 f32, 8 KB
    unsigned (*mbuf)[64] = (unsigned (*)[64])(smem + 8192);   // 64x64, 16 KB
    ushort_t* vbuf = (ushort_t*)(smem + 24576);               // 3 x 16 KB windows

    const int tid  = threadIdx.x;
    const int lane = tid & 63;
    const int wid  = tid >> 6;               // 0..7
    const int wq   = wid & 3;                // row group: rows wq*16..+15
    const int js   = wid >> 2;               // j-half of the 64j window
    const int quad = lane >> 4;
    const int l15  = lane & 15;
    const int bx   = blockIdx.x;
    const int half = bx & 1;
    const int h    = (bx >> 1) & 3;
    const int i0   = (bx >> 3) << 6;         // 64-row tile
    const int jbase = half << 11;            // 0 or 2048

    const float C1 = 1.44269504f;             // log2(e)

    for (int j = tid; j < 2048; j += 512) srs[j] = sr[h * N_NODES + jbase + j] * C1;
    for (int t = tid; t < 64 * 64; t += 512) {
        int r = t >> 6, c = t & 63;
        mbuf[r][c ^ r] = Apack[(size_t)(i0 + r) * 128 + (half << 6) + c];
    }
    const int myrow = wq * 16 + l15;
    const float slv = sl[h * N_NODES + i0 + myrow] * C1;
    __syncthreads();    // staging visible; no DMA issued yet

    float4v acc[8];
    #pragma unroll
    for (int nt = 0; nt < 8; ++nt)
        #pragma unroll
        for (int e = 0; e < 4; ++e) acc[nt][e] = 0.f;
    float4v accden;
    #pragma unroll
    for (int e = 0; e < 4; ++e) accden[e] = 0.f;

    short8 ones;
    #pragma unroll
    for (int e = 0; e < 8; ++e) ones[e] = (short)0x3F80;   // bf16 1.0

    // Window = 64j x 128d (16 KB), row d at 128B stride (64 ushorts).
    // Wave wid stages d-rows [wid*16, +16) in 2 calls of 8 rows.
    // Lane L -> d-row base + (L>>3), slot L&7; slot s of row d holds global
    // j-chunk s ^ (d&7)  (d&7 == (L>>3)&7 since bases are multiples of 8).
    const int dl  = lane >> 3;                       // 0..7
    const int gch = (lane & 7) ^ dl;                 // pre-swizzled source chunk
    const ushort_t* g0 = WhT + (size_t)(h * DK + wid * 16 + dl) * N_NODES
                             + jbase + gch * 8;

    #define DMA_WIN(BUF, IW)                                                         \
        {   ushort_t* lb_ = vbuf + (BUF) * 8192 + wid * 1024;                        \
            const ushort_t* gs_ = g0 + (IW) * 64;                                    \
            _Pragma("unroll")                                                        \
            for (int q_ = 0; q_ < 2; ++q_)                                           \
                __builtin_amdgcn_global_load_lds(                                    \
                    (const __attribute__((address_space(1))) void*)(gs_ + (size_t)q_ * 8 * N_NODES), \
                    (__attribute__((address_space(3))) void*)(lb_ + q_ * 512),       \
                    16, 0, 0);                                                       \
        }

    DMA_WIN(0, 0)
    DMA_WIN(1, 1)

    const int rs = ((js * 4 + quad) ^ (l15 & 7)) * 8;   // read slot (ushorts), v15 formula

    #pragma unroll 1
    for (int iw = 0; iw < 32; ++iw) {
        const unsigned wa = mbuf[myrow][(iw * 2 + js) ^ myrow];
        const float4v s0 = *(const float4v*)&srs[iw * 64 + js * 32 + quad * 8];
        const float4v s1 = *(const float4v*)&srs[iw * 64 + js * 32 + quad * 8 + 4];

        short8 pf;
        #pragma unroll
        for (int jj = 0; jj < 8; ++jj) {
            const int bit = quad * 8 + jj;
            float srj = (jj < 4) ? s0[jj] : s1[jj - 4];
            float x = slv + srj;                        // both *C1
            float t = fmaxf(x, x * 0.2f);
            t = ((wa >> bit) & 1u) ? t : -1e30f;
            pf[jj] = (short)(ushort_t)(__float_as_uint(__builtin_amdgcn_exp2f(t)) >> 16);
        }

        if (iw == 31) { asm volatile("s_waitcnt vmcnt(0)" ::: "memory"); }
        else          { asm volatile("s_waitcnt vmcnt(2)" ::: "memory"); }
        asm volatile("s_barrier" ::: "memory");   // window iw landed for ALL waves;
                                                  // all waves' iw-1 reads are done
        if (iw < 30) DMA_WIN((iw + 2) % 3, iw + 2)

        const ushort_t* vB = vbuf + (iw % 3) * 8192;
        #pragma unroll
        for (int nt = 0; nt < 8; ++nt) {
            short8 b = *(const short8*)(vB + (nt * 16 + l15) * 64 + rs);
            acc[nt] = __builtin_amdgcn_mfma_f32_16x16x32_bf16(pf, b, acc[nt], 0, 0, 0);
        }
        accden = __builtin_amdgcn_mfma_f32_16x16x32_bf16(pf, ones, accden, 0, 0, 0);
    }
    #undef DMA_WIN

    // ---- epilogue: merge js=1 into js=0 (pairs share rows), then store ----
    float* red  = (float*)(smem + 24576);             // 4 wq x 16 x 128 f32 = 32 KB
    float* lsum = (float*)(smem + 24576 + 32768);     // 4 wq x 16 f32
    __syncthreads();                                   // all DMAs drained (vmcnt 0)

    if (js == 1) {
        #pragma unroll
        for (int nt = 0; nt < 8; ++nt)
            #pragma unroll
            for (int r = 0; r < 4; ++r)
                red[wq * 2048 + (quad * 4 + r) * 128 + nt * 16 + l15] = acc[nt][r];
        if (l15 == 0) {
            #pragma unroll
            for (int r = 0; r < 4; ++r)
                lsum[wq * 16 + quad * 4 + r] = accden[r];
        }
    }
    __syncthreads();
    if (js == 0) {
        float* Np = Npart + (size_t)half * N_NODES * ODIM;
        #pragma unroll
        for (int nt = 0; nt < 8; ++nt)
            #pragma unroll
            for (int r = 0; r < 4; ++r) {
                const int rowi = wq * 16 + quad * 4 + r;
                float v = acc[nt][r] + red[wq * 2048 + (quad * 4 + r) * 128 + nt * 16 + l15];
                Np[(size_t)(i0 + rowi) * ODIM + h * DK + nt * 16 + l15] = v;
            }
        if (l15 == 0) {
            #pragma unroll
            for (int r = 0; r < 4; ++r) {
                const int rowi = wq * 16 + quad * 4 + r;
                Dpart[(half * 4 + h) * N_NODES + i0 + rowi] =
                    accden[r] + lsum[wq * 16 + quad * 4 + r];
            }
        }
    }
}

// ---------------------------------------------------------------------------
// Kernel 4: merge halves, normalize, elu, store (dual-dtype out).
// ---------------------------------------------------------------------------
__global__ __launch_bounds__(256) void merge_k(const float* __restrict__ Npart,
                                               const float* __restrict__ Dpart,
                                               void* __restrict__ out,
                                               const int* __restrict__ flag)
{
    const int f32 = *flag;
    const size_t e4 = ((size_t)blockIdx.x * 256 + threadIdx.x) * 4;
    const int i = (int)(e4 >> 9);
    const int c = (int)(e4 & 511);
    const int h = c >> 7;
    const float4v n0 = *(const float4v*)(Npart + e4);
    const float4v n1 = *(const float4v*)(Npart + (size_t)N_NODES * ODIM + e4);
    const float den = Dpart[h * N_NODES + i] + Dpart[(4 + h) * N_NODES + i];
    const float rinv = 1.0f / fmaxf(den, 1e-37f);
    const float C1 = 1.44269504f;
    float o[4];
    #pragma unroll
    for (int k = 0; k < 4; ++k) {
        float v = (n0[k] + n1[k]) * rinv;
        float e = __builtin_amdgcn_exp2f(v * C1) - 1.0f;
        o[k] = (v > 0.f) ? v : e;
    }
    if (f32) {
        float4v ov;
        #pragma unroll
        for (int k = 0; k < 4; ++k) ov[k] = o[k];
        *(float4v*)((float*)out + e4) = ov;
    } else {
        short4v ov;
        #pragma unroll
        for (int k = 0; k < 4; ++k) ov[k] = (short)f2bf_rne(o[k]);
        *(short4v*)((ushort_t*)out + e4) = ov;
    }
}

// ---------------------------------------------------------------------------
// Fallback single-pass attention (R5 structure) if ws too small for partials.
// ---------------------------------------------------------------------------
__global__ __launch_bounds__(256, 2) void attn_single_k(const ushort_t* __restrict__ WhT,
                                                        const unsigned* __restrict__ Apack,
                                                        const float* __restrict__ sl,
                                                        const float* __restrict__ sr,
                                                        void* __restrict__ out,
                                                        const int* __restrict__ flag)
{
    __shared__ float    srs[N_NODES];
    __shared__ unsigned mbuf[32][128];
    __shared__ float    red[2][32][128];
    __shared__ float    lsum[4][32];

    const int f32  = *flag;
    const int tid  = threadIdx.x;
    const int lane = tid & 63;
    const int wq   = tid >> 6;
    const int quad = lane >> 4;
    const int l15  = lane & 15;
    const int h    = blockIdx.x & 3;
    const int i0   = (blockIdx.x >> 2) << 5;

    for (int j = tid; j < N_NODES; j += 256) srs[j] = sr[h * N_NODES + j];
    for (int t = tid; t < 32 * 128; t += 256) {
        int r = t >> 7, c = t & 127;
        mbuf[r][c] = Apack[(size_t)(i0 + r) * 128 + c];
    }
    const float slv0 = sl[h * N_NODES + i0 + l15];
    const float slv1 = sl[h * N_NODES + i0 + 16 + l15];
    __syncthreads();

    const float C1 = 1.44269504f;
    const float C2 = 0.2f * 1.44269504f;

    float4v acc[2][8];
    #pragma unroll
    for (int mg = 0; mg < 2; ++mg)
        #pragma unroll
        for (int nt = 0; nt < 8; ++nt)
            #pragma unroll
            for (int e = 0; e < 4; ++e) acc[mg][nt][e] = 0.f;
    float lacc0 = 0.f, lacc1 = 0.f;

    const ushort_t* vb = WhT + (size_t)(h * DK + l15) * N_NODES + wq * 1024 + quad * 8;

    #pragma unroll 1
    for (int it = 0; it < 16; ++it) {
        const int jl = it * 64;
        const int j0 = wq * 1024 + jl;
        const int mc = j0 >> 5;

        short8 bf[8][2];
        #pragma unroll
        for (int nt = 0; nt < 8; ++nt) {
            bf[nt][0] = *(const short8*)(vb + (size_t)nt * 16 * N_NODES + jl);
            bf[nt][1] = *(const short8*)(vb + (size_t)nt * 16 * N_NODES + jl + 32);
        }

        const unsigned wa0 = mbuf[l15][mc],      wa1 = mbuf[l15][mc + 1];
        const unsigned wb0 = mbuf[16 + l15][mc], wb1 = mbuf[16 + l15][mc + 1];

        short8 pf0[2], pf1[2];
        #pragma unroll
        for (int s = 0; s < 2; ++s) {
            const float* sp = &srs[j0 + s * 32 + quad * 8];
            const float4v s0 = *(const float4v*)sp;
            const float4v s1 = *(const float4v*)(sp + 4);
            const unsigned wa = s ? wa1 : wa0;
            const unsigned wb = s ? wb1 : wb0;
            #pragma unroll
            for (int jj = 0; jj < 8; ++jj) {
                float srj = (jj < 4) ? s0[jj] : s1[jj - 4];
                int bit = quad * 8 + jj;
                float x0 = slv0 + srj;
                float t0 = fmaxf(x0 * C1, x0 * C2);
                t0 = ((wa >> bit) & 1u) ? t0 : -1e30f;
                float p0 = __builtin_amdgcn_exp2f(t0);
                ushort_t h0 = (ushort_t)(__float_as_uint(p0) >> 16);
                lacc0 += bf2f(h0);
                pf0[s][jj] = (short)h0;
                float x1 = slv1 + srj;
                float t1 = fmaxf(x1 * C1, x1 * C2);
                t1 = ((wb >> bit) & 1u) ? t1 : -1e30f;
                float p1 = __builtin_amdgcn_exp2f(t1);
                ushort_t h1 = (ushort_t)(__float_as_uint(p1) >> 16);
                lacc1 += bf2f(h1);
                pf1[s][jj] = (short)h1;
            }
        }

        #pragma unroll
        for (int nt = 0; nt < 8; ++nt) {
            acc[0][nt] = __builtin_amdgcn_mfma_f32_16x16x32_bf16(pf0[0], bf[nt][0], acc[0][nt], 0, 0, 0);
            acc[0][nt] = __builtin_amdgcn_mfma_f32_16x16x32_bf16(pf0[1], bf[nt][1], acc[0][nt], 0, 0, 0);
            acc[1][nt] = __builtin_amdgcn_mfma_f32_16x16x32_bf16(pf1[0], bf[nt][0], acc[1][nt], 0, 0, 0);
            acc[1][nt] = __builtin_amdgcn_mfma_f32_16x16x32_bf16(pf1[1], bf[nt][1], acc[1][nt], 0, 0, 0);
        }
    }

    lacc0 += __shfl_xor(lacc0, 16);
    lacc0 += __shfl_xor(lacc0, 32);
    lacc1 += __shfl_xor(lacc1, 16);
    lacc1 += __shfl_xor(lacc1, 32);
    if (lane < 16) {
        lsum[wq][l15]      = lacc0;
        lsum[wq][16 + l15] = lacc1;
    }
    if (wq >= 2) {
        #pragma unroll
        for (int mg = 0; mg < 2; ++mg)
            #pragma unroll
            for (int nt = 0; nt < 8; ++nt)
                #pragma unroll
                for (int r = 0; r < 4; ++r)
                    red[wq - 2][mg * 16 + quad * 4 + r][nt * 16 + l15] = acc[mg][nt][r];
    }
    __syncthreads();
    if (wq < 2) {
        #pragma unroll
        for (int mg = 0; mg < 2; ++mg)
            #pragma unroll
            for (int nt = 0; nt < 8; ++nt)
                #pragma unroll
                for (int r = 0; r < 4; ++r)
                    acc[mg][nt][r] += red[wq][mg * 16 + quad * 4 + r][nt * 16 + l15];
    }
    __syncthreads();
    if (wq == 1) {
        #pragma unroll
        for (int mg = 0; mg < 2; ++mg)
            #pragma unroll
            for (int nt = 0; nt < 8; ++nt)
                #pragma unroll
                for (int r = 0; r < 4; ++r)
                    red[0][mg * 16 + quad * 4 + r][nt * 16 + l15] = acc[mg][nt][r];
    }
    __syncthreads();
    if (wq == 0) {
        #pragma unroll
        for (int mg = 0; mg < 2; ++mg) {
            float linv[4];
            #pragma unroll
            for (int r = 0; r < 4; ++r) {
                int rowi = mg * 16 + quad * 4 + r;
                float den = lsum[0][rowi] + lsum[1][rowi] + lsum[2][rowi] + lsum[3][rowi];
                linv[r] = 1.0f / fmaxf(den, 1e-37f);
            }
            #pragma unroll
            for (int nt = 0; nt < 8; ++nt)
                #pragma unroll
                for (int r = 0; r < 4; ++r) {
                    int rowi = mg * 16 + quad * 4 + r;
                    float v = (acc[mg][nt][r] + red[0][rowi][nt * 16 + l15]) * linv[r];
                    float e = __builtin_amdgcn_exp2f(v * C1) - 1.0f;
                    float o = (v > 0.f) ? v : e;
                    size_t oidx = (size_t)(i0 + rowi) * ODIM + h * DK + nt * 16 + l15;
                    if (f32) ((float*)out)[oidx] = o;
                    else     ((ushort_t*)out)[oidx] = f2bf_rne(o);
                }
        }
    }
}

// ---------------------------------------------------------------------------
extern "C" void kernel_launch(void* const* d_in, const int* in_sizes, int n_in,
                              void* d_out, int out_size, void* d_ws, size_t ws_size,
                              hipStream_t stream)
{
    const void* H  = d_in[0];
    const int*  A  = (const int*)d_in[1];
    const void* W  = d_in[2];
    const void* al = d_in[3];
    const void* ar = d_in[4];

    if (ws_size < (7u << 20)) return;

    char* ws = (char*)d_ws;
    ushort_t* WhT   = (ushort_t*)ws;                                    // 4 MB
    unsigned long long* Apack = (unsigned long long*)(ws + (4u << 20)); // 2 MB
    ushort_t* WT    = (ushort_t*)(ws + (6u << 20));                     // 512 KB
    float*    sl    = (float*)(ws + (6u << 20) + (512u << 10));         // 64 KB
    float*    sr    = (float*)(ws + (6u << 20) + (576u << 10));         // 64 KB
    int*      flag  = (int*)(ws + (6u << 20) + (640u << 10));           // 4 B
    float*    Npart = (float*)(ws + (12u << 20));                       // 16 MB
    float*    Dpart = (float*)(ws + (28u << 20));                       // 128 KB
    const bool have_split = ws_size >= (29u << 20);

    pack_mask_k    <<<16384, 256, 0, stream>>>(A, Apack, (const ushort_t*)H, flag,
                                               W, WT, sl, sr);
    gemm_wht_dual_k<<<512,   256, 0, stream>>>(H, WT, WhT, flag, al, ar, sl, sr);
    if (have_split) {
        attn_split_k<<<512, 512, 0, stream>>>(WhT, (const unsigned*)Apack, sl, sr, Npart, Dpart);
        merge_k     <<<2048, 256, 0, stream>>>(Npart, Dpart, (void*)d_out, flag);
    } else {
        attn_single_k<<<512, 256, 0, stream>>>(WhT, (const unsigned*)Apack, sl, sr, (void*)d_out, flag);
    }
}

// Round 8
// 171.064 us; speedup vs baseline: 1.0088x; 1.0088x over previous
//
#include <hip/hip_runtime.h>

typedef unsigned short ushort_t;
typedef __attribute__((ext_vector_type(8)))  short  short8;
typedef __attribute__((ext_vector_type(4)))  short  short4v;
typedef __attribute__((ext_vector_type(4)))  float  float4v;
typedef __attribute__((ext_vector_type(4)))  int    int4v;

#define N_NODES 4096
#define NHEADS  4
#define DK      128
#define ODIM    512
#define KDIM    512

__device__ __forceinline__ float bf2f(ushort_t u) {
    return __uint_as_float(((unsigned)u) << 16);
}
__device__ __forceinline__ ushort_t f2bf_rne(float f) {
    unsigned u = __float_as_uint(f);
    u += 0x7fffu + ((u >> 16) & 1u);
    return (ushort_t)(u >> 16);
}

// ---------------------------------------------------------------------------
// Kernel 1 (fused): mask bit-pack + dtype flag + W transpose + sl/sr zeroing.
// ---------------------------------------------------------------------------
__global__ __launch_bounds__(256) void pack_mask_k(const int* __restrict__ A,
                                                   unsigned long long* __restrict__ P,
                                                   const ushort_t* __restrict__ Hraw,
                                                   int* __restrict__ flag,
                                                   const void* __restrict__ W,
                                                   ushort_t* __restrict__ WT,
                                                   float* __restrict__ sl,
                                                   float* __restrict__ sr)
{
    __shared__ ushort_t lt[64][72];
    __shared__ int dcnt[4];
    const int tid = threadIdx.x;
    const int bx  = blockIdx.x;

    if (bx == 0 && tid < 64) {
        const int lane = tid;
        int cnt = 0;
        #pragma unroll
        for (int s = 0; s < 16; ++s) {
            ushort_t v = Hraw[(lane * 16 + s) * 2];
            int e = (v >> 7) & 0xFF;
            cnt += (((e >= 90) && (e <= 140)) || (v == 0)) ? 1 : 0;
        }
        #pragma unroll
        for (int off = 32; off; off >>= 1) cnt += __shfl_down(cnt, off);
        if (lane == 0) *flag = (cnt < 768) ? 1 : 0;
    }

    // ---- mask pack (all blocks) ----
    {
        const int lane  = tid & 63;
        const int flat4 = bx * 256 + tid;             // index in units of int4
        const int row   = flat4 >> 10;                // (flat4*4) >> 12
        const int col0  = (flat4 << 2) & 4095;
        const int4v a   = ((const int4v*)A)[flat4];
        unsigned nib = 0;
        #pragma unroll
        for (int j = 0; j < 4; ++j)
            nib |= ((a[j] != 0) || (row == col0 + j)) ? (1u << j) : 0u;
        unsigned long long v = (unsigned long long)nib << ((lane & 15) * 4);
        v |= __shfl_xor(v, 1);
        v |= __shfl_xor(v, 2);
        v |= __shfl_xor(v, 4);
        v |= __shfl_xor(v, 8);
        if ((lane & 15) == 0) P[flat4 >> 4] = v;
    }

    // ---- zero sl/sr (blocks 64..95): 8192 threads x one float4 ----
    if (bx >= 64 && bx < 96) {
        const int idx = (bx - 64) * 256 + tid;        // 0..8191
        float4v z;
        #pragma unroll
        for (int e = 0; e < 4; ++e) z[e] = 0.f;
        if (idx < 4096) ((float4v*)sl)[idx] = z;
        else            ((float4v*)sr)[idx - 4096] = z;
    }

    // ---- W transpose (blocks 0..63) ----
    if (bx < 64) {
        // block-local dtype detection (same 1024 samples as the global flag)
        int cnt = 0;
        #pragma unroll
        for (int s = 0; s < 4; ++s) {
            ushort_t v = Hraw[(tid * 4 + s) * 2];
            int e = (v >> 7) & 0xFF;
            cnt += (((e >= 90) && (e <= 140)) || (v == 0)) ? 1 : 0;
        }
        #pragma unroll
        for (int off = 32; off; off >>= 1) cnt += __shfl_down(cnt, off);
        if ((tid & 63) == 0) dcnt[tid >> 6] = cnt;
        __syncthreads();
        const int f32 = (dcnt[0] + dcnt[1] + dcnt[2] + dcnt[3]) < 768;

        const int ti = bx >> 3, tj = bx & 7;
        const int r = tid >> 2, c2 = tid & 3;
        const size_t eo = (size_t)(ti * 64 + r) * KDIM + tj * 64 + c2 * 16;
        if (f32) {
            const float4v* src = (const float4v*)((const float*)W + eo);
            float4v f0 = src[0], f1 = src[1], f2 = src[2], f3 = src[3];
            #pragma unroll
            for (int e = 0; e < 4; ++e) {
                lt[r][c2 * 16 +  0 + e] = f2bf_rne(f0[e]);
                lt[r][c2 * 16 +  4 + e] = f2bf_rne(f1[e]);
                lt[r][c2 * 16 +  8 + e] = f2bf_rne(f2[e]);
                lt[r][c2 * 16 + 12 + e] = f2bf_rne(f3[e]);
            }
        } else {
            const short8* src = (const short8*)((const ushort_t*)W + eo);
            short8 v0 = src[0];
            short8 v1 = src[1];
            *(short8*)&lt[r][c2 * 16]     = v0;
            *(short8*)&lt[r][c2 * 16 + 8] = v1;
        }
        __syncthreads();
        #pragma unroll
        for (int itr = 0; itr < 2; ++itr) {
            int idx = itr * 256 + tid;
            int n = idx >> 3, c = idx & 7;
            short8 vv;
            #pragma unroll
            for (int e = 0; e < 8; ++e) vv[e] = (short)lt[c * 8 + e][n];
            *(short8*)(WT + (size_t)(tj * 64 + n) * KDIM + ti * 64 + c * 8) = vv;
        }
    }
}

// ---------------------------------------------------------------------------
// Kernel 2 (fused): WhT[n][i] = (H @ W)[i][n] + sl/sr partial accumulation.
// ---------------------------------------------------------------------------
__global__ __launch_bounds__(256) void gemm_wht_dual_k(const void* __restrict__ H,
                                                       const ushort_t* __restrict__ WT,
                                                       ushort_t* __restrict__ WhT,
                                                       const int* __restrict__ flag,
                                                       const void* __restrict__ al,
                                                       const void* __restrict__ ar,
                                                       float* __restrict__ sl,
                                                       float* __restrict__ sr)
{
    __shared__ ushort_t lt[64][72];
    const int f32 = *flag;
    const int tid  = threadIdx.x;
    const int lane = tid & 63;
    const int wid  = tid >> 6;
    const int quad = lane >> 4;
    const int l15  = lane & 15;
    const int bm = blockIdx.x & 63, bn = blockIdx.x >> 6;
    const int i0 = bm * 64, n0 = bn * 64;

    const size_t aoff = (size_t)(i0 + wid * 16 + l15) * KDIM + quad * 8;
    const short8* bp0 = (const short8*)(WT + (size_t)(n0 +  0 + l15) * KDIM) + quad;
    const short8* bp1 = (const short8*)(WT + (size_t)(n0 + 16 + l15) * KDIM) + quad;
    const short8* bp2 = (const short8*)(WT + (size_t)(n0 + 32 + l15) * KDIM) + quad;
    const short8* bp3 = (const short8*)(WT + (size_t)(n0 + 48 + l15) * KDIM) + quad;

    float4v acc0, acc1, acc2, acc3;
    #pragma unroll
    for (int e = 0; e < 4; ++e) { acc0[e] = 0.f; acc1[e] = 0.f; acc2[e] = 0.f; acc3[e] = 0.f; }

    #pragma unroll 4
    for (int k8 = 0; k8 < 64; k8 += 4) {
        short8 a;
        if (f32) {
            const float4v* fp = (const float4v*)((const float*)H + aoff + (size_t)k8 * 8);
            float4v x0 = fp[0], x1 = fp[1];
            #pragma unroll
            for (int e = 0; e < 4; ++e) {
                a[e]     = (short)f2bf_rne(x0[e]);
                a[4 + e] = (short)f2bf_rne(x1[e]);
            }
        } else {
            a = *(const short8*)((const ushort_t*)H + aoff + (size_t)k8 * 8);
        }
        acc0 = __builtin_amdgcn_mfma_f32_16x16x32_bf16(a, bp0[k8], acc0, 0, 0, 0);
        acc1 = __builtin_amdgcn_mfma_f32_16x16x32_bf16(a, bp1[k8], acc1, 0, 0, 0);
        acc2 = __builtin_amdgcn_mfma_f32_16x16x32_bf16(a, bp2[k8], acc2, 0, 0, 0);
        acc3 = __builtin_amdgcn_mfma_f32_16x16x32_bf16(a, bp3[k8], acc3, 0, 0, 0);
    }

    #pragma unroll
    for (int r = 0; r < 4; ++r) {
        int m = wid * 16 + quad * 4 + r;
        lt[ 0 + l15][m] = f2bf_rne(acc0[r]);
        lt[16 + l15][m] = f2bf_rne(acc1[r]);
        lt[32 + l15][m] = f2bf_rne(acc2[r]);
        lt[48 + l15][m] = f2bf_rne(acc3[r]);
    }
    __syncthreads();
    #pragma unroll
    for (int itr = 0; itr < 2; ++itr) {
        int idx = itr * 256 + tid;
        int n = idx >> 3, c = idx & 7;
        short8 v = *(const short8*)&lt[n][c * 8];
        *(short8*)(WhT + (size_t)(n0 + n) * N_NODES + i0 + c * 8) = v;
    }

    // ---- fused slsr partials over this block's 64 d-values ----
    {
        const int h2 = n0 >> 7;          // head
        const int d0 = n0 & 127;         // d offset within head
        const int m  = tid >> 2;         // output row = i0 + m
        const int part = tid & 3;
        float psl = 0.f, psr = 0.f;
        #pragma unroll
        for (int k = 0; k < 16; ++k) {
            int n = part * 16 + k;
            float wv = bf2f(lt[n][m]);
            float av = f32 ? ((const float*)al)[h2 * DK + d0 + n]
                           : bf2f(((const ushort_t*)al)[h2 * DK + d0 + n]);
            float bv = f32 ? ((const float*)ar)[h2 * DK + d0 + n]
                           : bf2f(((const ushort_t*)ar)[h2 * DK + d0 + n]);
            psl += wv * av;
            psr += wv * bv;
        }
        psl += __shfl_down(psl, 2); psl += __shfl_down(psl, 1);
        psr += __shfl_down(psr, 2); psr += __shfl_down(psr, 1);
        if (part == 0) {
            atomicAdd(&sl[h2 * N_NODES + i0 + m], psl);
            atomicAdd(&sr[h2 * N_NODES + i0 + m], psr);
        }
    }
}

// ---------------------------------------------------------------------------
// Kernel 3 v18: full-j blocks -> merge_k eliminated.
// Block = 64 rows x one head x ALL 4096 j; 1024 threads = 16 waves =
// (row-group wq 0..3) x (j-substream js 0..3) of a shared 128j x 128d
// (32 KB) window.  Grid 256 = 1 block/CU (144 KB LDS), 16 waves/CU =
// 4 waves/SIMD (same as v17) but: barrier count per unit work halves,
// denominators complete in-block -> normalize+ELU+store DIRECTLY to out
// (writes 16.5 MB Npart -> 4 MB bf16), merge_k and its 32 MB round-trip
// gone.  Pipeline identical to v17: 3-buffer rotation, counted vmcnt(2)
// (2 DMA calls/wave/window), one raw s_barrier per window, DMA iw+2
// post-barrier.  h = bx&3 -> each XCD serves one head (1 MB V slice,
// L2-resident).
// Swizzles (both-sides-derived): window row d = 256B (16 slots of 16B);
// slot s of row d holds global j-chunk s ^ (d&7) (pre-swizzled DMA src:
// lane L, call q: chunk = (L&15) ^ (q*4 + (L>>4))); read slot
// (js*4+quad) ^ (l15&7) -> every bank exactly 2 accesses (free, m136).
// mbuf[64][128] col c ^ (r&31) -> 16 distinct banks on the 16-lane read.
// ---------------------------------------------------------------------------
__global__ __launch_bounds__(1024, 4) void attn_full_k(const ushort_t* __restrict__ WhT,
                                                       const unsigned* __restrict__ Apack,
                                                       const float* __restrict__ sl,
                                                       const float* __restrict__ sr,
                                                       void* __restrict__ out,
                                                       const int* __restrict__ flag)
{
    __shared__ char smem[147456] __attribute__((aligned(16)));
    ushort_t* vbuf = (ushort_t*)smem;                          // 3 x 32 KB windows
    unsigned (*mbuf)[128] = (unsigned (*)[128])(smem + 98304); // 64 x 128, 32 KB
    float*    srs  = (float*)(smem + 131072);                  // 4096 f32, 16 KB

    const int f32  = *flag;
    const int tid  = threadIdx.x;
    const int lane = tid & 63;
    const int wid  = tid >> 6;               // 0..15
    const int wq   = wid & 3;                // row group: rows wq*16..+15
    const int js   = wid >> 2;               // j substream 0..3 (32j of the 128j window)
    const int quad = lane >> 4;
    const int l15  = lane & 15;
    const int bx   = blockIdx.x;
    const int h    = bx & 3;                 // head; bx&7 -> XCD serves one head
    const int i0   = (bx >> 2) << 6;         // 64-row tile

    const float C1 = 1.44269504f;             // log2(e)

    for (int j = tid; j < 4096; j += 1024) srs[j] = sr[h * N_NODES + j] * C1;
    for (int t = tid; t < 64 * 128; t += 1024) {
        int r = t >> 7, c = t & 127;
        mbuf[r][c ^ (r & 31)] = Apack[(size_t)(i0 + r) * 128 + c];
    }
    const int myrow = wq * 16 + l15;
    const float slv = sl[h * N_NODES + i0 + myrow] * C1;
    __syncthreads();    // staging visible; no DMA issued yet

    float4v acc[8];
    #pragma unroll
    for (int nt = 0; nt < 8; ++nt)
        #pragma unroll
        for (int e = 0; e < 4; ++e) acc[nt][e] = 0.f;
    float4v accden;
    #pragma unroll
    for (int e = 0; e < 4; ++e) accden[e] = 0.f;

    short8 ones;
    #pragma unroll
    for (int e = 0; e < 8; ++e) ones[e] = (short)0x3F80;   // bf16 1.0

    // DMA: window = 128j x 128d (32 KB), row d = 256B.  Wave wid stages
    // d-rows [wid*8, +8) via 2 calls of 4 rows x 256B.  Lane L -> row
    // base + (L>>4), slot L&15; slot s of row d holds chunk s ^ (d&7),
    // d&7 = q*4 + (L>>4) for call q.
    const int dl = lane >> 4;                        // 0..3
    const int s4 = lane & 15;
    const ushort_t* gq0 = WhT + (size_t)(h * DK + wid * 8 + 0 + dl) * N_NODES
                              + (size_t)((s4 ^ (0 + dl)) * 8);
    const ushort_t* gq1 = WhT + (size_t)(h * DK + wid * 8 + 4 + dl) * N_NODES
                              + (size_t)((s4 ^ (4 + dl)) * 8);

    #define DMA_WIN(BUF, IW)                                                           \
        {   ushort_t* lb_ = vbuf + (BUF) * 16384 + wid * 1024;                         \
            __builtin_amdgcn_global_load_lds(                                          \
                (const __attribute__((address_space(1))) void*)(gq0 + (size_t)(IW) * 128), \
                (__attribute__((address_space(3))) void*)(lb_), 16, 0, 0);             \
            __builtin_amdgcn_global_load_lds(                                          \
                (const __attribute__((address_space(1))) void*)(gq1 + (size_t)(IW) * 128), \
                (__attribute__((address_space(3))) void*)(lb_ + 512), 16, 0, 0);       \
        }

    DMA_WIN(0, 0)
    DMA_WIN(1, 1)

    const int rs = ((js * 4 + quad) ^ (l15 & 7)) * 8;   // read slot offset (ushorts)

    #pragma unroll 1
    for (int iw = 0; iw < 32; ++iw) {
        const unsigned wa = mbuf[myrow][(iw * 4 + js) ^ (myrow & 31)];
        const float4v s0 = *(const float4v*)&srs[iw * 128 + js * 32 + quad * 8];
        const float4v s1 = *(const float4v*)&srs[iw * 128 + js * 32 + quad * 8 + 4];

        short8 pf;
        #pragma unroll
        for (int jj = 0; jj < 8; ++jj) {
            const int bit = quad * 8 + jj;
            float srj = (jj < 4) ? s0[jj] : s1[jj - 4];
            float x = slv + srj;                        // both *C1
            float t = fmaxf(x, x * 0.2f);
            t = ((wa >> bit) & 1u) ? t : -1e30f;
            pf[jj] = (short)(ushort_t)(__float_as_uint(__builtin_amdgcn_exp2f(t)) >> 16);
        }

        if (iw == 31) { asm volatile("s_waitcnt vmcnt(0)" ::: "memory"); }
        else          { asm volatile("s_waitcnt vmcnt(2)" ::: "memory"); }
        asm volatile("s_barrier" ::: "memory");   // window iw landed for ALL waves;
                                                  // all waves' iw-1 reads are done
        if (iw < 30) DMA_WIN((iw + 2) % 3, iw + 2)

        const ushort_t* vB = vbuf + (iw % 3) * 16384;
        #pragma unroll
        for (int nt = 0; nt < 8; ++nt) {
            short8 b = *(const short8*)(vB + (nt * 16 + l15) * 128 + rs);
            acc[nt] = __builtin_amdgcn_mfma_f32_16x16x32_bf16(pf, b, acc[nt], 0, 0, 0);
        }
        accden = __builtin_amdgcn_mfma_f32_16x16x32_bf16(pf, ones, accden, 0, 0, 0);
    }
    #undef DMA_WIN

    // ---- epilogue: reduce js 1..3 into js 0, normalize, elu, store ----
    float* red  = (float*)smem;                       // [3][4wq][16][128] f32 = 96 KB
    float* lsum = (float*)(smem + 98304);             // [4js][64] f32
    __syncthreads();                                   // vmcnt(0) drained; all reads done

    if (js != 0) {
        float* rp = red + (size_t)((js - 1) * 4 + wq) * 2048;
        #pragma unroll
        for (int nt = 0; nt < 8; ++nt)
            #pragma unroll
            for (int r = 0; r < 4; ++r)
                rp[(quad * 4 + r) * 128 + nt * 16 + l15] = acc[nt][r];
        if (l15 == 0) {
            #pragma unroll
            for (int r = 0; r < 4; ++r)
                lsum[js * 64 + wq * 16 + quad * 4 + r] = accden[r];
        }
    }
    __syncthreads();
    if (js == 0) {
        float rinv[4];
        #pragma unroll
        for (int r = 0; r < 4; ++r) {
            const int rowo = wq * 16 + quad * 4 + r;
            float den = accden[r] + lsum[64 + rowo] + lsum[128 + rowo] + lsum[192 + rowo];
            rinv[r] = 1.0f / fmaxf(den, 1e-37f);
        }
        #pragma unroll
        for (int nt = 0; nt < 8; ++nt)
            #pragma unroll
            for (int r = 0; r < 4; ++r) {
                const int ri = (quad * 4 + r) * 128 + nt * 16 + l15;
                float v = (acc[nt][r]
                           + red[(size_t)(0 * 4 + wq) * 2048 + ri]
                           + red[(size_t)(1 * 4 + wq) * 2048 + ri]
                           + red[(size_t)(2 * 4 + wq) * 2048 + ri]) * rinv[r];
                float e = __builtin_amdgcn_exp2f(v * C1) - 1.0f;
                float o = (v > 0.f) ? v : e;
                const size_t oidx = (size_t)(i0 + wq * 16 + quad * 4 + r) * ODIM
                                  + h * DK + nt * 16 + l15;
                if (f32) ((float*)out)[oidx] = o;
                else     ((ushort_t*)out)[oidx] = f2bf_rne(o);
            }
    }
}

// ---------------------------------------------------------------------------
extern "C" void kernel_launch(void* const* d_in, const int* in_sizes, int n_in,
                              void* d_out, int out_size, void* d_ws, size_t ws_size,
                              hipStream_t stream)
{
    const void* H  = d_in[0];
    const int*  A  = (const int*)d_in[1];
    const void* W  = d_in[2];
    const void* al = d_in[3];
    const void* ar = d_in[4];

    if (ws_size < (7u << 20)) return;

    char* ws = (char*)d_ws;
    ushort_t* WhT   = (ushort_t*)ws;                                    // 4 MB
    unsigned long long* Apack = (unsigned long long*)(ws + (4u << 20)); // 2 MB
    ushort_t* WT    = (ushort_t*)(ws + (6u << 20));                     // 512 KB
    float*    sl    = (float*)(ws + (6u << 20) + (512u << 10));         // 64 KB
    float*    sr    = (float*)(ws + (6u << 20) + (576u << 10));         // 64 KB
    int*      flag  = (int*)(ws + (6u << 20) + (640u << 10));           // 4 B

    pack_mask_k    <<<16384, 256, 0, stream>>>(A, Apack, (const ushort_t*)H, flag,
                                               W, WT, sl, sr);
    gemm_wht_dual_k<<<512,   256, 0, stream>>>(H, WT, WhT, flag, al, ar, sl, sr);
    attn_full_k    <<<256,  1024, 0, stream>>>(WhT, (const unsigned*)Apack, sl, sr,
                                               (void*)d_out, flag);
}

// Round 9
// 159.591 us; speedup vs baseline: 1.0813x; 1.0719x over previous
//
#include <hip/hip_runtime.h>

typedef unsigned short ushort_t;
typedef __attribute__((ext_vector_type(8)))  short  short8;
typedef __attribute__((ext_vector_type(4)))  short  short4v;
typedef __attribute__((ext_vector_type(4)))  float  float4v;
typedef __attribute__((ext_vector_type(4)))  int    int4v;

#define N_NODES 4096
#define NHEADS  4
#define DK      128
#define ODIM    512
#define KDIM    512

__device__ __forceinline__ float bf2f(ushort_t u) {
    return __uint_as_float(((unsigned)u) << 16);
}
__device__ __forceinline__ ushort_t f2bf_rne(float f) {
    unsigned u = __float_as_uint(f);
    u += 0x7fffu + ((u >> 16) & 1u);
    return (ushort_t)(u >> 16);
}

// ---------------------------------------------------------------------------
// Kernel 1 (fused): mask bit-pack + dtype flag + W transpose + sl/sr zeroing.
// v19: 4096 blocks x 4 int4/thread (was 16384 x 1) — less dispatch ramp on
// the 64 MB A read.
// ---------------------------------------------------------------------------
__global__ __launch_bounds__(256) void pack_mask_k(const int* __restrict__ A,
                                                   unsigned long long* __restrict__ P,
                                                   const ushort_t* __restrict__ Hraw,
                                                   int* __restrict__ flag,
                                                   const void* __restrict__ W,
                                                   ushort_t* __restrict__ WT,
                                                   float* __restrict__ sl,
                                                   float* __restrict__ sr)
{
    __shared__ ushort_t lt[64][72];
    __shared__ int dcnt[4];
    const int tid = threadIdx.x;
    const int bx  = blockIdx.x;

    if (bx == 0 && tid < 64) {
        const int lane = tid;
        int cnt = 0;
        #pragma unroll
        for (int s = 0; s < 16; ++s) {
            ushort_t v = Hraw[(lane * 16 + s) * 2];
            int e = (v >> 7) & 0xFF;
            cnt += (((e >= 90) && (e <= 140)) || (v == 0)) ? 1 : 0;
        }
        #pragma unroll
        for (int off = 32; off; off >>= 1) cnt += __shfl_down(cnt, off);
        if (lane == 0) *flag = (cnt < 768) ? 1 : 0;
    }

    // ---- mask pack (all blocks): 4 int4 per thread ----
    {
        const int lane = tid & 63;
        #pragma unroll
        for (int kk = 0; kk < 4; ++kk) {
            const int flat4 = (bx * 4 + kk) * 256 + tid;   // index in units of int4
            const int row   = flat4 >> 10;                 // (flat4*4) >> 12
            const int col0  = (flat4 << 2) & 4095;
            const int4v a   = ((const int4v*)A)[flat4];
            unsigned nib = 0;
            #pragma unroll
            for (int j = 0; j < 4; ++j)
                nib |= ((a[j] != 0) || (row == col0 + j)) ? (1u << j) : 0u;
            unsigned long long v = (unsigned long long)nib << ((lane & 15) * 4);
            v |= __shfl_xor(v, 1);
            v |= __shfl_xor(v, 2);
            v |= __shfl_xor(v, 4);
            v |= __shfl_xor(v, 8);
            if ((lane & 15) == 0) P[flat4 >> 4] = v;
        }
    }

    // ---- zero sl/sr (blocks 64..95): 8192 threads x one float4 ----
    if (bx >= 64 && bx < 96) {
        const int idx = (bx - 64) * 256 + tid;        // 0..8191
        float4v z;
        #pragma unroll
        for (int e = 0; e < 4; ++e) z[e] = 0.f;
        if (idx < 4096) ((float4v*)sl)[idx] = z;
        else            ((float4v*)sr)[idx - 4096] = z;
    }

    // ---- W transpose (blocks 0..63) ----
    if (bx < 64) {
        // block-local dtype detection (same 1024 samples as the global flag)
        int cnt = 0;
        #pragma unroll
        for (int s = 0; s < 4; ++s) {
            ushort_t v = Hraw[(tid * 4 + s) * 2];
            int e = (v >> 7) & 0xFF;
            cnt += (((e >= 90) && (e <= 140)) || (v == 0)) ? 1 : 0;
        }
        #pragma unroll
        for (int off = 32; off; off >>= 1) cnt += __shfl_down(cnt, off);
        if ((tid & 63) == 0) dcnt[tid >> 6] = cnt;
        __syncthreads();
        const int f32 = (dcnt[0] + dcnt[1] + dcnt[2] + dcnt[3]) < 768;

        const int ti = bx >> 3, tj = bx & 7;
        const int r = tid >> 2, c2 = tid & 3;
        const size_t eo = (size_t)(ti * 64 + r) * KDIM + tj * 64 + c2 * 16;
        if (f32) {
            const float4v* src = (const float4v*)((const float*)W + eo);
            float4v f0 = src[0], f1 = src[1], f2 = src[2], f3 = src[3];
            #pragma unroll
            for (int e = 0; e < 4; ++e) {
                lt[r][c2 * 16 +  0 + e] = f2bf_rne(f0[e]);
                lt[r][c2 * 16 +  4 + e] = f2bf_rne(f1[e]);
                lt[r][c2 * 16 +  8 + e] = f2bf_rne(f2[e]);
                lt[r][c2 * 16 + 12 + e] = f2bf_rne(f3[e]);
            }
        } else {
            const short8* src = (const short8*)((const ushort_t*)W + eo);
            short8 v0 = src[0];
            short8 v1 = src[1];
            *(short8*)&lt[r][c2 * 16]     = v0;
            *(short8*)&lt[r][c2 * 16 + 8] = v1;
        }
        __syncthreads();
        #pragma unroll
        for (int itr = 0; itr < 2; ++itr) {
            int idx = itr * 256 + tid;
            int n = idx >> 3, c = idx & 7;
            short8 vv;
            #pragma unroll
            for (int e = 0; e < 8; ++e) vv[e] = (short)lt[c * 8 + e][n];
            *(short8*)(WT + (size_t)(tj * 64 + n) * KDIM + ti * 64 + c * 8) = vv;
        }
    }
}

// ---------------------------------------------------------------------------
// Kernel 2 v19: WhT = (H @ W)^T with LDS-staged B panel.
// Diagnosis: the old loop fed MFMA straight from GLOBAL B pointers
// (bp0[k8]...) — the exact v11 anti-pattern (L2 latency on the MFMA chain),
// and each of the 4 waves fetched the same B panel (4x redundancy).  v19
// pre-stages the block's full B panel (64 n x 512 k bf16 = 64 KB) in LDS:
// one global_load_lds per row (64 lanes x 16B = exactly the 1 KB row),
// 16 calls/wave, then vmcnt(0)+barrier once.  K-loop B reads become
// ds_read_b128.  Swizzle (both-sides): LDS slot t of row n holds global
// chunk t^(n&3); read slot (quad+k8)^(l15&3) -> per-8-lane beat 2-way
// (free, m136).  LDS 64K + 9K lt = 73.7 KB -> 2 blocks/CU, grid 512 =
// one residency round.  A path (dual-dtype cvt) unchanged.
// ---------------------------------------------------------------------------
__global__ __launch_bounds__(256) void gemm_wht_dual_k(const void* __restrict__ H,
                                                       const ushort_t* __restrict__ WT,
                                                       ushort_t* __restrict__ WhT,
                                                       const int* __restrict__ flag,
                                                       const void* __restrict__ al,
                                                       const void* __restrict__ ar,
                                                       float* __restrict__ sl,
                                                       float* __restrict__ sr)
{
    __shared__ ushort_t Bs[64 * KDIM];   // 64 KB staged B panel (slot-swizzled)
    __shared__ ushort_t lt[64][72];
    const int f32 = *flag;
    const int tid  = threadIdx.x;
    const int lane = tid & 63;
    const int wid  = tid >> 6;
    const int quad = lane >> 4;
    const int l15  = lane & 15;
    const int bm = blockIdx.x & 63, bn = blockIdx.x >> 6;
    const int i0 = bm * 64, n0 = bn * 64;

    // ---- stage B panel: wave wid stages rows wid*16 .. +15, 1 call/row ----
    #pragma unroll
    for (int rr = 0; rr < 16; ++rr) {
        const int n = wid * 16 + rr;
        const ushort_t* src = WT + (size_t)(n0 + n) * KDIM + (size_t)((lane ^ (n & 3)) * 8);
        __builtin_amdgcn_global_load_lds(
            (const __attribute__((address_space(1))) void*)src,
            (__attribute__((address_space(3))) void*)(Bs + n * KDIM), 16, 0, 0);
    }
    asm volatile("s_waitcnt vmcnt(0)" ::: "memory");
    __syncthreads();

    const size_t aoff = (size_t)(i0 + wid * 16 + l15) * KDIM + quad * 8;

    float4v acc0, acc1, acc2, acc3;
    #pragma unroll
    for (int e = 0; e < 4; ++e) { acc0[e] = 0.f; acc1[e] = 0.f; acc2[e] = 0.f; acc3[e] = 0.f; }

    const int sx = l15 & 3;   // read-slot XOR (matches stage pre-swizzle)

    #pragma unroll 4
    for (int k8 = 0; k8 < 64; k8 += 4) {
        short8 a;
        if (f32) {
            const float4v* fp = (const float4v*)((const float*)H + aoff + (size_t)k8 * 8);
            float4v x0 = fp[0], x1 = fp[1];
            #pragma unroll
            for (int e = 0; e < 4; ++e) {
                a[e]     = (short)f2bf_rne(x0[e]);
                a[4 + e] = (short)f2bf_rne(x1[e]);
            }
        } else {
            a = *(const short8*)((const ushort_t*)H + aoff + (size_t)k8 * 8);
        }
        const int s = (quad + k8) ^ sx;
        short8 b0 = *(const short8*)(Bs + ( 0 + l15) * KDIM + s * 8);
        short8 b1 = *(const short8*)(Bs + (16 + l15) * KDIM + s * 8);
        short8 b2 = *(const short8*)(Bs + (32 + l15) * KDIM + s * 8);
        short8 b3 = *(const short8*)(Bs + (48 + l15) * KDIM + s * 8);
        acc0 = __builtin_amdgcn_mfma_f32_16x16x32_bf16(a, b0, acc0, 0, 0, 0);
        acc1 = __builtin_amdgcn_mfma_f32_16x16x32_bf16(a, b1, acc1, 0, 0, 0);
        acc2 = __builtin_amdgcn_mfma_f32_16x16x32_bf16(a, b2, acc2, 0, 0, 0);
        acc3 = __builtin_amdgcn_mfma_f32_16x16x32_bf16(a, b3, acc3, 0, 0, 0);
    }

    #pragma unroll
    for (int r = 0; r < 4; ++r) {
        int m = wid * 16 + quad * 4 + r;
        lt[ 0 + l15][m] = f2bf_rne(acc0[r]);
        lt[16 + l15][m] = f2bf_rne(acc1[r]);
        lt[32 + l15][m] = f2bf_rne(acc2[r]);
        lt[48 + l15][m] = f2bf_rne(acc3[r]);
    }
    __syncthreads();
    #pragma unroll
    for (int itr = 0; itr < 2; ++itr) {
        int idx = itr * 256 + tid;
        int n = idx >> 3, c = idx & 7;
        short8 v = *(const short8*)&lt[n][c * 8];
        *(short8*)(WhT + (size_t)(n0 + n) * N_NODES + i0 + c * 8) = v;
    }

    // ---- fused slsr partials over this block's 64 d-values ----
    {
        const int h2 = n0 >> 7;          // head
        const int d0 = n0 & 127;         // d offset within head
        const int m  = tid >> 2;         // output row = i0 + m
        const int part = tid & 3;
        float psl = 0.f, psr = 0.f;
        #pragma unroll
        for (int k = 0; k < 16; ++k) {
            int n = part * 16 + k;
            float wv = bf2f(lt[n][m]);
            float av = f32 ? ((const float*)al)[h2 * DK + d0 + n]
                           : bf2f(((const ushort_t*)al)[h2 * DK + d0 + n]);
            float bv = f32 ? ((const float*)ar)[h2 * DK + d0 + n]
                           : bf2f(((const ushort_t*)ar)[h2 * DK + d0 + n]);
            psl += wv * av;
            psr += wv * bv;
        }
        psl += __shfl_down(psl, 2); psl += __shfl_down(psl, 1);
        psr += __shfl_down(psr, 2); psr += __shfl_down(psr, 1);
        if (part == 0) {
            atomicAdd(&sl[h2 * N_NODES + i0 + m], psl);
            atomicAdd(&sr[h2 * N_NODES + i0 + m], psr);
        }
    }
}

// ---------------------------------------------------------------------------
// Kernel 3 v18 (unchanged — control this round): full-j blocks, 16 waves,
// shared 128j x 128d windows, denominators complete in-block, direct store.
// ---------------------------------------------------------------------------
__global__ __launch_bounds__(1024, 4) void attn_full_k(const ushort_t* __restrict__ WhT,
                                                       const unsigned* __restrict__ Apack,
                                                       const float* __restrict__ sl,
                                                       const float* __restrict__ sr,
                                                       void* __restrict__ out,
                                                       const int* __restrict__ flag)
{
    __shared__ char smem[147456] __attribute__((aligned(16)));
    ushort_t* vbuf = (ushort_t*)smem;                          // 3 x 32 KB windows
    unsigned (*mbuf)[128] = (unsigned (*)[128])(smem + 98304); // 64 x 128, 32 KB
    float*    srs  = (float*)(smem + 131072);                  // 4096 f32, 16 KB

    const int f32  = *flag;
    const int tid  = threadIdx.x;
    const int lane = tid & 63;
    const int wid  = tid >> 6;               // 0..15
    const int wq   = wid & 3;                // row group: rows wq*16..+15
    const int js   = wid >> 2;               // j substream 0..3 (32j of the 128j window)
    const int quad = lane >> 4;
    const int l15  = lane & 15;
    const int bx   = blockIdx.x;
    const int h    = bx & 3;                 // head; bx&7 -> XCD serves one head
    const int i0   = (bx >> 2) << 6;         // 64-row tile

    const float C1 = 1.44269504f;             // log2(e)

    for (int j = tid; j < 4096; j += 1024) srs[j] = sr[h * N_NODES + j] * C1;
    for (int t = tid; t < 64 * 128; t += 1024) {
        int r = t >> 7, c = t & 127;
        mbuf[r][c ^ (r & 31)] = Apack[(size_t)(i0 + r) * 128 + c];
    }
    const int myrow = wq * 16 + l15;
    const float slv = sl[h * N_NODES + i0 + myrow] * C1;
    __syncthreads();    // staging visible; no DMA issued yet

    float4v acc[8];
    #pragma unroll
    for (int nt = 0; nt < 8; ++nt)
        #pragma unroll
        for (int e = 0; e < 4; ++e) acc[nt][e] = 0.f;
    float4v accden;
    #pragma unroll
    for (int e = 0; e < 4; ++e) accden[e] = 0.f;

    short8 ones;
    #pragma unroll
    for (int e = 0; e < 8; ++e) ones[e] = (short)0x3F80;   // bf16 1.0

    const int dl = lane >> 4;                        // 0..3
    const int s4 = lane & 15;
    const ushort_t* gq0 = WhT + (size_t)(h * DK + wid * 8 + 0 + dl) * N_NODES
                              + (size_t)((s4 ^ (0 + dl)) * 8);
    const ushort_t* gq1 = WhT + (size_t)(h * DK + wid * 8 + 4 + dl) * N_NODES
                              + (size_t)((s4 ^ (4 + dl)) * 8);

    #define DMA_WIN(BUF, IW)                                                           \
        {   ushort_t* lb_ = vbuf + (BUF) * 16384 + wid * 1024;                         \
            __builtin_amdgcn_global_load_lds(                                          \
                (const __attribute__((address_space(1))) void*)(gq0 + (size_t)(IW) * 128), \
                (__attribute__((address_space(3))) void*)(lb_), 16, 0, 0);             \
            __builtin_amdgcn_global_load_lds(                                          \
                (const __attribute__((address_space(1))) void*)(gq1 + (size_t)(IW) * 128), \
                (__attribute__((address_space(3))) void*)(lb_ + 512), 16, 0, 0);       \
        }

    DMA_WIN(0, 0)
    DMA_WIN(1, 1)

    const int rs = ((js * 4 + quad) ^ (l15 & 7)) * 8;   // read slot offset (ushorts)

    #pragma unroll 1
    for (int iw = 0; iw < 32; ++iw) {
        const unsigned wa = mbuf[myrow][(iw * 4 + js) ^ (myrow & 31)];
        const float4v s0 = *(const float4v*)&srs[iw * 128 + js * 32 + quad * 8];
        const float4v s1 = *(const float4v*)&srs[iw * 128 + js * 32 + quad * 8 + 4];

        short8 pf;
        #pragma unroll
        for (int jj = 0; jj < 8; ++jj) {
            const int bit = quad * 8 + jj;
            float srj = (jj < 4) ? s0[jj] : s1[jj - 4];
            float x = slv + srj;                        // both *C1
            float t = fmaxf(x, x * 0.2f);
            t = ((wa >> bit) & 1u) ? t : -1e30f;
            pf[jj] = (short)(ushort_t)(__float_as_uint(__builtin_amdgcn_exp2f(t)) >> 16);
        }

        if (iw == 31) { asm volatile("s_waitcnt vmcnt(0)" ::: "memory"); }
        else          { asm volatile("s_waitcnt vmcnt(2)" ::: "memory"); }
        asm volatile("s_barrier" ::: "memory");   // window iw landed for ALL waves;
                                                  // all waves' iw-1 reads are done
        if (iw < 30) DMA_WIN((iw + 2) % 3, iw + 2)

        const ushort_t* vB = vbuf + (iw % 3) * 16384;
        #pragma unroll
        for (int nt = 0; nt < 8; ++nt) {
            short8 b = *(const short8*)(vB + (nt * 16 + l15) * 128 + rs);
            acc[nt] = __builtin_amdgcn_mfma_f32_16x16x32_bf16(pf, b, acc[nt], 0, 0, 0);
        }
        accden = __builtin_amdgcn_mfma_f32_16x16x32_bf16(pf, ones, accden, 0, 0, 0);
    }
    #undef DMA_WIN

    // ---- epilogue: reduce js 1..3 into js 0, normalize, elu, store ----
    float* red  = (float*)smem;                       // [3][4wq][16][128] f32 = 96 KB
    float* lsum = (float*)(smem + 98304);             // [4js][64] f32
    __syncthreads();                                   // vmcnt(0) drained; all reads done

    if (js != 0) {
        float* rp = red + (size_t)((js - 1) * 4 + wq) * 2048;
        #pragma unroll
        for (int nt = 0; nt < 8; ++nt)
            #pragma unroll
            for (int r = 0; r < 4; ++r)
                rp[(quad * 4 + r) * 128 + nt * 16 + l15] = acc[nt][r];
        if (l15 == 0) {
            #pragma unroll
            for (int r = 0; r < 4; ++r)
                lsum[js * 64 + wq * 16 + quad * 4 + r] = accden[r];
        }
    }
    __syncthreads();
    if (js == 0) {
        float rinv[4];
        #pragma unroll
        for (int r = 0; r < 4; ++r) {
            const int rowo = wq * 16 + quad * 4 + r;
            float den = accden[r] + lsum[64 + rowo] + lsum[128 + rowo] + lsum[192 + rowo];
            rinv[r] = 1.0f / fmaxf(den, 1e-37f);
        }
        #pragma unroll
        for (int nt = 0; nt < 8; ++nt)
            #pragma unroll
            for (int r = 0; r < 4; ++r) {
                const int ri = (quad * 4 + r) * 128 + nt * 16 + l15;
                float v = (acc[nt][r]
                           + red[(size_t)(0 * 4 + wq) * 2048 + ri]
                           + red[(size_t)(1 * 4 + wq) * 2048 + ri]
                           + red[(size_t)(2 * 4 + wq) * 2048 + ri]) * rinv[r];
                float e = __builtin_amdgcn_exp2f(v * C1) - 1.0f;
                float o = (v > 0.f) ? v : e;
                const size_t oidx = (size_t)(i0 + wq * 16 + quad * 4 + r) * ODIM
                                  + h * DK + nt * 16 + l15;
                if (f32) ((float*)out)[oidx] = o;
                else     ((ushort_t*)out)[oidx] = f2bf_rne(o);
            }
    }
}

// ---------------------------------------------------------------------------
extern "C" void kernel_launch(void* const* d_in, const int* in_sizes, int n_in,
                              void* d_out, int out_size, void* d_ws, size_t ws_size,
                              hipStream_t stream)
{
    const void* H  = d_in[0];
    const int*  A  = (const int*)d_in[1];
    const void* W  = d_in[2];
    const void* al = d_in[3];
    const void* ar = d_in[4];

    if (ws_size < (7u << 20)) return;

    char* ws = (char*)d_ws;
    ushort_t* WhT   = (ushort_t*)ws;                                    // 4 MB
    unsigned long long* Apack = (unsigned long long*)(ws + (4u << 20)); // 2 MB
    ushort_t* WT    = (ushort_t*)(ws + (6u << 20));                     // 512 KB
    float*    sl    = (float*)(ws + (6u << 20) + (512u << 10));         // 64 KB
    float*    sr    = (float*)(ws + (6u << 20) + (576u << 10));         // 64 KB
    int*      flag  = (int*)(ws + (6u << 20) + (640u << 10));           // 4 B

    pack_mask_k    <<<4096,  256, 0, stream>>>(A, Apack, (const ushort_t*)H, flag,
                                               W, WT, sl, sr);
    gemm_wht_dual_k<<<512,   256, 0, stream>>>(H, WT, WhT, flag, al, ar, sl, sr);
    attn_full_k    <<<256,  1024, 0, stream>>>(WhT, (const unsigned*)Apack, sl, sr,
                                               (void*)d_out, flag);
}

// Round 10
// 158.862 us; speedup vs baseline: 1.0862x; 1.0046x over previous
//
#include <hip/hip_runtime.h>

typedef unsigned short ushort_t;
typedef __attribute__((ext_vector_type(8)))  short  short8;
typedef __attribute__((ext_vector_type(4)))  short  short4v;
typedef __attribute__((ext_vector_type(4)))  float  float4v;
typedef __attribute__((ext_vector_type(4)))  int    int4v;

#define N_NODES 4096
#define NHEADS  4
#define DK      128
#define ODIM    512
#define KDIM    512

__device__ __forceinline__ float bf2f(ushort_t u) {
    return __uint_as_float(((unsigned)u) << 16);
}
__device__ __forceinline__ ushort_t f2bf_rne(float f) {
    unsigned u = __float_as_uint(f);
    u += 0x7fffu + ((u >> 16) & 1u);
    return (ushort_t)(u >> 16);
}

// ---------------------------------------------------------------------------
// Kernel 1 (fused): mask bit-pack + dtype flag + W transpose + sl/sr zeroing.
// ---------------------------------------------------------------------------
__global__ __launch_bounds__(256) void pack_mask_k(const int* __restrict__ A,
                                                   unsigned long long* __restrict__ P,
                                                   const ushort_t* __restrict__ Hraw,
                                                   int* __restrict__ flag,
                                                   const void* __restrict__ W,
                                                   ushort_t* __restrict__ WT,
                                                   float* __restrict__ sl,
                                                   float* __restrict__ sr)
{
    __shared__ ushort_t lt[64][72];
    __shared__ int dcnt[4];
    const int tid = threadIdx.x;
    const int bx  = blockIdx.x;

    if (bx == 0 && tid < 64) {
        const int lane = tid;
        int cnt = 0;
        #pragma unroll
        for (int s = 0; s < 16; ++s) {
            ushort_t v = Hraw[(lane * 16 + s) * 2];
            int e = (v >> 7) & 0xFF;
            cnt += (((e >= 90) && (e <= 140)) || (v == 0)) ? 1 : 0;
        }
        #pragma unroll
        for (int off = 32; off; off >>= 1) cnt += __shfl_down(cnt, off);
        if (lane == 0) *flag = (cnt < 768) ? 1 : 0;
    }

    // ---- mask pack (all blocks): 4 int4 per thread ----
    {
        const int lane = tid & 63;
        #pragma unroll
        for (int kk = 0; kk < 4; ++kk) {
            const int flat4 = (bx * 4 + kk) * 256 + tid;   // index in units of int4
            const int row   = flat4 >> 10;                 // (flat4*4) >> 12
            const int col0  = (flat4 << 2) & 4095;
            const int4v a   = ((const int4v*)A)[flat4];
            unsigned nib = 0;
            #pragma unroll
            for (int j = 0; j < 4; ++j)
                nib |= ((a[j] != 0) || (row == col0 + j)) ? (1u << j) : 0u;
            unsigned long long v = (unsigned long long)nib << ((lane & 15) * 4);
            v |= __shfl_xor(v, 1);
            v |= __shfl_xor(v, 2);
            v |= __shfl_xor(v, 4);
            v |= __shfl_xor(v, 8);
            if ((lane & 15) == 0) P[flat4 >> 4] = v;
        }
    }

    // ---- zero sl/sr (blocks 64..95): 8192 threads x one float4 ----
    if (bx >= 64 && bx < 96) {
        const int idx = (bx - 64) * 256 + tid;        // 0..8191
        float4v z;
        #pragma unroll
        for (int e = 0; e < 4; ++e) z[e] = 0.f;
        if (idx < 4096) ((float4v*)sl)[idx] = z;
        else            ((float4v*)sr)[idx - 4096] = z;
    }

    // ---- W transpose (blocks 0..63) ----
    if (bx < 64) {
        // block-local dtype detection (same 1024 samples as the global flag)
        int cnt = 0;
        #pragma unroll
        for (int s = 0; s < 4; ++s) {
            ushort_t v = Hraw[(tid * 4 + s) * 2];
            int e = (v >> 7) & 0xFF;
            cnt += (((e >= 90) && (e <= 140)) || (v == 0)) ? 1 : 0;
        }
        #pragma unroll
        for (int off = 32; off; off >>= 1) cnt += __shfl_down(cnt, off);
        if ((tid & 63) == 0) dcnt[tid >> 6] = cnt;
        __syncthreads();
        const int f32 = (dcnt[0] + dcnt[1] + dcnt[2] + dcnt[3]) < 768;

        const int ti = bx >> 3, tj = bx & 7;
        const int r = tid >> 2, c2 = tid & 3;
        const size_t eo = (size_t)(ti * 64 + r) * KDIM + tj * 64 + c2 * 16;
        if (f32) {
            const float4v* src = (const float4v*)((const float*)W + eo);
            float4v f0 = src[0], f1 = src[1], f2 = src[2], f3 = src[3];
            #pragma unroll
            for (int e = 0; e < 4; ++e) {
                lt[r][c2 * 16 +  0 + e] = f2bf_rne(f0[e]);
                lt[r][c2 * 16 +  4 + e] = f2bf_rne(f1[e]);
                lt[r][c2 * 16 +  8 + e] = f2bf_rne(f2[e]);
                lt[r][c2 * 16 + 12 + e] = f2bf_rne(f3[e]);
            }
        } else {
            const short8* src = (const short8*)((const ushort_t*)W + eo);
            short8 v0 = src[0];
            short8 v1 = src[1];
            *(short8*)&lt[r][c2 * 16]     = v0;
            *(short8*)&lt[r][c2 * 16 + 8] = v1;
        }
        __syncthreads();
        #pragma unroll
        for (int itr = 0; itr < 2; ++itr) {
            int idx = itr * 256 + tid;
            int n = idx >> 3, c = idx & 7;
            short8 vv;
            #pragma unroll
            for (int e = 0; e < 8; ++e) vv[e] = (short)lt[c * 8 + e][n];
            *(short8*)(WT + (size_t)(tj * 64 + n) * KDIM + ti * 64 + c * 8) = vv;
        }
    }
}

// ---------------------------------------------------------------------------
// Kernel 2 v19 (unchanged): WhT = (H @ W)^T with LDS-staged B panel + fused
// slsr partials.
// ---------------------------------------------------------------------------
__global__ __launch_bounds__(256) void gemm_wht_dual_k(const void* __restrict__ H,
                                                       const ushort_t* __restrict__ WT,
                                                       ushort_t* __restrict__ WhT,
                                                       const int* __restrict__ flag,
                                                       const void* __restrict__ al,
                                                       const void* __restrict__ ar,
                                                       float* __restrict__ sl,
                                                       float* __restrict__ sr)
{
    __shared__ ushort_t Bs[64 * KDIM];   // 64 KB staged B panel (slot-swizzled)
    __shared__ ushort_t lt[64][72];
    const int f32 = *flag;
    const int tid  = threadIdx.x;
    const int lane = tid & 63;
    const int wid  = tid >> 6;
    const int quad = lane >> 4;
    const int l15  = lane & 15;
    const int bm = blockIdx.x & 63, bn = blockIdx.x >> 6;
    const int i0 = bm * 64, n0 = bn * 64;

    // ---- stage B panel: wave wid stages rows wid*16 .. +15, 1 call/row ----
    #pragma unroll
    for (int rr = 0; rr < 16; ++rr) {
        const int n = wid * 16 + rr;
        const ushort_t* src = WT + (size_t)(n0 + n) * KDIM + (size_t)((lane ^ (n & 3)) * 8);
        __builtin_amdgcn_global_load_lds(
            (const __attribute__((address_space(1))) void*)src,
            (__attribute__((address_space(3))) void*)(Bs + n * KDIM), 16, 0, 0);
    }
    asm volatile("s_waitcnt vmcnt(0)" ::: "memory");
    __syncthreads();

    const size_t aoff = (size_t)(i0 + wid * 16 + l15) * KDIM + quad * 8;

    float4v acc0, acc1, acc2, acc3;
    #pragma unroll
    for (int e = 0; e < 4; ++e) { acc0[e] = 0.f; acc1[e] = 0.f; acc2[e] = 0.f; acc3[e] = 0.f; }

    const int sx = l15 & 3;   // read-slot XOR (matches stage pre-swizzle)

    #pragma unroll 4
    for (int k8 = 0; k8 < 64; k8 += 4) {
        short8 a;
        if (f32) {
            const float4v* fp = (const float4v*)((const float*)H + aoff + (size_t)k8 * 8);
            float4v x0 = fp[0], x1 = fp[1];
            #pragma unroll
            for (int e = 0; e < 4; ++e) {
                a[e]     = (short)f2bf_rne(x0[e]);
                a[4 + e] = (short)f2bf_rne(x1[e]);
            }
        } else {
            a = *(const short8*)((const ushort_t*)H + aoff + (size_t)k8 * 8);
        }
        const int s = (quad + k8) ^ sx;
        short8 b0 = *(const short8*)(Bs + ( 0 + l15) * KDIM + s * 8);
        short8 b1 = *(const short8*)(Bs + (16 + l15) * KDIM + s * 8);
        short8 b2 = *(const short8*)(Bs + (32 + l15) * KDIM + s * 8);
        short8 b3 = *(const short8*)(Bs + (48 + l15) * KDIM + s * 8);
        acc0 = __builtin_amdgcn_mfma_f32_16x16x32_bf16(a, b0, acc0, 0, 0, 0);
        acc1 = __builtin_amdgcn_mfma_f32_16x16x32_bf16(a, b1, acc1, 0, 0, 0);
        acc2 = __builtin_amdgcn_mfma_f32_16x16x32_bf16(a, b2, acc2, 0, 0, 0);
        acc3 = __builtin_amdgcn_mfma_f32_16x16x32_bf16(a, b3, acc3, 0, 0, 0);
    }

    #pragma unroll
    for (int r = 0; r < 4; ++r) {
        int m = wid * 16 + quad * 4 + r;
        lt[ 0 + l15][m] = f2bf_rne(acc0[r]);
        lt[16 + l15][m] = f2bf_rne(acc1[r]);
        lt[32 + l15][m] = f2bf_rne(acc2[r]);
        lt[48 + l15][m] = f2bf_rne(acc3[r]);
    }
    __syncthreads();
    #pragma unroll
    for (int itr = 0; itr < 2; ++itr) {
        int idx = itr * 256 + tid;
        int n = idx >> 3, c = idx & 7;
        short8 v = *(const short8*)&lt[n][c * 8];
        *(short8*)(WhT + (size_t)(n0 + n) * N_NODES + i0 + c * 8) = v;
    }

    // ---- fused slsr partials over this block's 64 d-values ----
    {
        const int h2 = n0 >> 7;          // head
        const int d0 = n0 & 127;         // d offset within head
        const int m  = tid >> 2;         // output row = i0 + m
        const int part = tid & 3;
        float psl = 0.f, psr = 0.f;
        #pragma unroll
        for (int k = 0; k < 16; ++k) {
            int n = part * 16 + k;
            float wv = bf2f(lt[n][m]);
            float av = f32 ? ((const float*)al)[h2 * DK + d0 + n]
                           : bf2f(((const ushort_t*)al)[h2 * DK + d0 + n]);
            float bv = f32 ? ((const float*)ar)[h2 * DK + d0 + n]
                           : bf2f(((const ushort_t*)ar)[h2 * DK + d0 + n]);
            psl += wv * av;
            psr += wv * bv;
        }
        psl += __shfl_down(psl, 2); psl += __shfl_down(psl, 1);
        psr += __shfl_down(psr, 2); psr += __shfl_down(psr, 1);
        if (part == 0) {
            atomicAdd(&sl[h2 * N_NODES + i0 + m], psl);
            atomicAdd(&sr[h2 * N_NODES + i0 + m], psr);
        }
    }
}

// ---------------------------------------------------------------------------
// Kernel 3 v20: big-window / trivial-sync attention.
// R9 diagnosis: attn slack = 32 barriers + counted-vmcnt waits + mask-LDS
// reads + 4.59M conflicts (256B rows used only 8/16 slots per wave).
// v20: window = 256j x 128d (64 KB), 2 buffers, ONE __syncthreads per
// window (its built-in vmcnt(0) drain is nominal: the prefetch was issued a
// full window (~2.8us compute) earlier, >> L2 latency).  Barriers 32 -> 16.
// Masks: register-prefetched global loads (2 u32/wave/window, L2-hot) —
// mbuf + its staging + its conflicts deleted.  V slot swizzle covers all
// 32 slots: slot s of row d holds global j-chunk s ^ (d&31) (pre-swizzled
// DMA source: lane L, call q: d = wid*8+q*2+(L>>5), chunk = (L&31)^(d&31));
// read slot (js*8+kk*4+quad) ^ (d&31) -> per-16-lane group spans 16 slots
// with fixed bit4 -> 8 bank-groups x 2 lanes = 2-way (free, m136).
// LDS 2x64K vbuf + 16K srs = 144 KB (1 block/CU, 4 waves/SIMD, as v18).
// setprio(1) around the MFMA cluster (T5; cheap, possibly null).
// ---------------------------------------------------------------------------
__global__ __launch_bounds__(1024, 4) void attn_full_k(const ushort_t* __restrict__ WhT,
                                                       const unsigned* __restrict__ Apack,
                                                       const float* __restrict__ sl,
                                                       const float* __restrict__ sr,
                                                       void* __restrict__ out,
                                                       const int* __restrict__ flag)
{
    __shared__ char smem[147456] __attribute__((aligned(16)));
    ushort_t* vbuf = (ushort_t*)smem;                 // 2 x 64 KB windows
    float*    srs  = (float*)(smem + 131072);         // 4096 f32, 16 KB

    const int f32  = *flag;
    const int tid  = threadIdx.x;
    const int lane = tid & 63;
    const int wid  = tid >> 6;               // 0..15
    const int wq   = wid & 3;                // row group: rows wq*16..+15
    const int js   = wid >> 2;               // j substream 0..3 (64j of the 256j window)
    const int quad = lane >> 4;
    const int l15  = lane & 15;
    const int bx   = blockIdx.x;
    const int h    = bx & 3;                 // head
    const int i0   = (bx >> 2) << 6;         // 64-row tile

    const float C1 = 1.44269504f;             // log2(e)

    for (int j = tid; j < 4096; j += 1024) srs[j] = sr[h * N_NODES + j] * C1;
    const int myrow = wq * 16 + l15;
    const float slv = sl[h * N_NODES + i0 + myrow] * C1;
    const unsigned* mrow = Apack + (size_t)(i0 + myrow) * 128;   // this row's mask words
    __syncthreads();    // srs visible

    float4v acc[8];
    #pragma unroll
    for (int nt = 0; nt < 8; ++nt)
        #pragma unroll
        for (int e = 0; e < 4; ++e) acc[nt][e] = 0.f;
    float4v accden;
    #pragma unroll
    for (int e = 0; e < 4; ++e) accden[e] = 0.f;

    short8 ones;
    #pragma unroll
    for (int e = 0; e < 8; ++e) ones[e] = (short)0x3F80;   // bf16 1.0

    // DMA: window = 256j x 128d (64 KB), row = 512 B (32 slots of 16 B).
    // Wave wid stages d-rows [wid*8, +8) via 4 calls of 2 rows.
    const int rrow  = lane >> 5;             // 0..1
    const int s32   = lane & 31;
    const int dbase = wid * 8;

    #define DMA_WIN(BUF, W)                                                            \
        { _Pragma("unroll")                                                            \
          for (int q_ = 0; q_ < 4; ++q_) {                                             \
            const int d_  = dbase + q_ * 2 + rrow;                                     \
            const int ch_ = s32 ^ (d_ & 31);                                           \
            const ushort_t* g_ = WhT + (size_t)(h * DK + d_) * N_NODES                 \
                                      + (size_t)(W) * 256 + (size_t)ch_ * 8;           \
            __builtin_amdgcn_global_load_lds(                                          \
                (const __attribute__((address_space(1))) void*)g_,                     \
                (__attribute__((address_space(3))) void*)(vbuf + (BUF) * 32768         \
                                                         + wid * 2048 + q_ * 512),     \
                16, 0, 0);                                                             \
          } }

    unsigned wa0 = mrow[js * 2 + 0];
    unsigned wa1 = mrow[js * 2 + 1];
    DMA_WIN(0, 0)

    #pragma unroll 1
    for (int w = 0; w < 16; ++w) {
        __syncthreads();                     // drains vmcnt: window w + masks landed
        unsigned wa0n = wa0, wa1n = wa1;
        if (w < 15) {
            wa0n = mrow[(w + 1) * 8 + js * 2 + 0];
            wa1n = mrow[(w + 1) * 8 + js * 2 + 1];
            DMA_WIN((w + 1) & 1, w + 1)
        }

        const float4v a0 = *(const float4v*)&srs[w * 256 + js * 64 + quad * 8];
        const float4v a1 = *(const float4v*)&srs[w * 256 + js * 64 + quad * 8 + 4];
        const float4v b0 = *(const float4v*)&srs[w * 256 + js * 64 + 32 + quad * 8];
        const float4v b1 = *(const float4v*)&srs[w * 256 + js * 64 + 32 + quad * 8 + 4];

        short8 pf0, pf1;
        #pragma unroll
        for (int jj = 0; jj < 8; ++jj) {
            const int bit = quad * 8 + jj;
            float x = slv + ((jj < 4) ? a0[jj] : a1[jj - 4]);   // both *C1
            float t = fmaxf(x, x * 0.2f);
            t = ((wa0 >> bit) & 1u) ? t : -1e30f;
            pf0[jj] = (short)(ushort_t)(__float_as_uint(__builtin_amdgcn_exp2f(t)) >> 16);
            float y = slv + ((jj < 4) ? b0[jj] : b1[jj - 4]);
            float u = fmaxf(y, y * 0.2f);
            u = ((wa1 >> bit) & 1u) ? u : -1e30f;
            pf1[jj] = (short)(ushort_t)(__float_as_uint(__builtin_amdgcn_exp2f(u)) >> 16);
        }

        const ushort_t* vB = vbuf + (w & 1) * 32768;
        __builtin_amdgcn_s_setprio(1);
        #pragma unroll
        for (int nt = 0; nt < 8; ++nt) {
            const int roff  = (nt * 16 + l15) * 256;            // ushorts
            const int dlow  = (nt & 1) * 16 + l15;              // d&31 of this row
            const int slot0 = (js * 8 + 0 + quad) ^ dlow;
            const int slot1 = (js * 8 + 4 + quad) ^ dlow;
            short8 bv0 = *(const short8*)(vB + roff + slot0 * 8);
            short8 bv1 = *(const short8*)(vB + roff + slot1 * 8);
            acc[nt] = __builtin_amdgcn_mfma_f32_16x16x32_bf16(pf0, bv0, acc[nt], 0, 0, 0);
            acc[nt] = __builtin_amdgcn_mfma_f32_16x16x32_bf16(pf1, bv1, acc[nt], 0, 0, 0);
        }
        accden = __builtin_amdgcn_mfma_f32_16x16x32_bf16(pf0, ones, accden, 0, 0, 0);
        accden = __builtin_amdgcn_mfma_f32_16x16x32_bf16(pf1, ones, accden, 0, 0, 0);
        __builtin_amdgcn_s_setprio(0);

        wa0 = wa0n; wa1 = wa1n;
    }
    #undef DMA_WIN

    // ---- epilogue: reduce js 1..3 into js 0, normalize, elu, store ----
    float* red  = (float*)smem;                       // [3][4wq][16][128] f32 = 96 KB
    float* lsum = (float*)(smem + 98304);             // [4js][64] f32
    __syncthreads();                                   // all DMAs drained; reads done

    if (js != 0) {
        float* rp = red + (size_t)((js - 1) * 4 + wq) * 2048;
        #pragma unroll
        for (int nt = 0; nt < 8; ++nt)
            #pragma unroll
            for (int r = 0; r < 4; ++r)
                rp[(quad * 4 + r) * 128 + nt * 16 + l15] = acc[nt][r];
        if (l15 == 0) {
            #pragma unroll
            for (int r = 0; r < 4; ++r)
                lsum[js * 64 + wq * 16 + quad * 4 + r] = accden[r];
        }
    }
    __syncthreads();
    if (js == 0) {
        float rinv[4];
        #pragma unroll
        for (int r = 0; r < 4; ++r) {
            const int rowo = wq * 16 + quad * 4 + r;
            float den = accden[r] + lsum[64 + rowo] + lsum[128 + rowo] + lsum[192 + rowo];
            rinv[r] = 1.0f / fmaxf(den, 1e-37f);
        }
        #pragma unroll
        for (int nt = 0; nt < 8; ++nt)
            #pragma unroll
            for (int r = 0; r < 4; ++r) {
                const int ri = (quad * 4 + r) * 128 + nt * 16 + l15;
                float v = (acc[nt][r]
                           + red[(size_t)(0 * 4 + wq) * 2048 + ri]
                           + red[(size_t)(1 * 4 + wq) * 2048 + ri]
                           + red[(size_t)(2 * 4 + wq) * 2048 + ri]) * rinv[r];
                float e = __builtin_amdgcn_exp2f(v * C1) - 1.0f;
                float o = (v > 0.f) ? v : e;
                const size_t oidx = (size_t)(i0 + wq * 16 + quad * 4 + r) * ODIM
                                  + h * DK + nt * 16 + l15;
                if (f32) ((float*)out)[oidx] = o;
                else     ((ushort_t*)out)[oidx] = f2bf_rne(o);
            }
    }
}

// ---------------------------------------------------------------------------
extern "C" void kernel_launch(void* const* d_in, const int* in_sizes, int n_in,
                              void* d_out, int out_size, void* d_ws, size_t ws_size,
                              hipStream_t stream)
{
    const void* H  = d_in[0];
    const int*  A  = (const int*)d_in[1];
    const void* W  = d_in[2];
    const void* al = d_in[3];
    const void* ar = d_in[4];

    if (ws_size < (7u << 20)) return;

    char* ws = (char*)d_ws;
    ushort_t* WhT   = (ushort_t*)ws;                                    // 4 MB
    unsigned long long* Apack = (unsigned long long*)(ws + (4u << 20)); // 2 MB
    ushort_t* WT    = (ushort_t*)(ws + (6u << 20));                     // 512 KB
    float*    sl    = (float*)(ws + (6u << 20) + (512u << 10));         // 64 KB
    float*    sr    = (float*)(ws + (6u << 20) + (576u << 10));         // 64 KB
    int*      flag  = (int*)(ws + (6u << 20) + (640u << 10));           // 4 B

    pack_mask_k    <<<4096,  256, 0, stream>>>(A, Apack, (const ushort_t*)H, flag,
                                               W, WT, sl, sr);
    gemm_wht_dual_k<<<512,   256, 0, stream>>>(H, WT, WhT, flag, al, ar, sl, sr);
    attn_full_k    <<<256,  1024, 0, stream>>>(WhT, (const unsigned*)Apack, sl, sr,
                                               (void*)d_out, flag);
}